// Round 1
// baseline (593.839 us; speedup 1.0000x reference)
//
#include <hip/hip_runtime.h>
#include <hip/hip_bf16.h>

#define BB 8
#define CC 64
#define HH 256
#define WW 256

__device__ __forceinline__ unsigned short f2bf(float f) {
    __hip_bfloat16 h = __float2bfloat16(f);   // RNE
    return *reinterpret_cast<unsigned short*>(&h);
}
__device__ __forceinline__ float bf2f(unsigned short u) {
    unsigned int v = ((unsigned int)u) << 16;
    float r;
    __builtin_memcpy(&r, &v, 4);
    return r;
}
__device__ __forceinline__ float bflo(unsigned int u) {   // low ushort -> float
    unsigned int v = u << 16;
    float r; __builtin_memcpy(&r, &v, 4); return r;
}
__device__ __forceinline__ float bfhi(unsigned int u) {   // high ushort -> float
    unsigned int v = u & 0xffff0000u;
    float r; __builtin_memcpy(&r, &v, 4); return r;
}

// ---------------------------------------------------------------------------
// K1: fused 5x5 depthwise (pad 2) + 1x21 horizontal depthwise (pad 10)
// All LDS traffic as explicit float4 (guaranteed ds_read_b128 / ds_write_b128,
// 16B lane stride -> conflict-free).  Strip of 8 rows x (b,c), 512 threads:
// wave w -> row w, lane l -> cols 4l..4l+3.  Writes attn2 as bf16.
// ---------------------------------------------------------------------------
__global__ __launch_bounds__(512) void k1_local_h(
        const float* __restrict__ x, const float* __restrict__ lw,
        const float* __restrict__ hw, unsigned short* __restrict__ a2out) {
    const int strip = blockIdx.x;          // 0..31
    const int bc    = blockIdx.y;          // 0..511
    const int c     = bc & (CC - 1);
    const int y0    = strip * 8;
    const int tid   = threadIdx.x;

    // xs4[rr][g]: x row (y0-2+rr), float4 group g covers gx = 4g-4 .. 4g-1 (g 0..65)
    __shared__ float4 xs4[12][66];
    // a1_4[r][g]: 5x5 output row (y0+r), group g covers xc = 4g-12 .. 4g-9 (g 0..69)
    // valid xc 0..255 -> groups 3..66; groups 0..2 / 67..69 are zero pad (h-conv pad 10)
    __shared__ float4 a1_4[8][70];

    const float* xbase = x + (size_t)bc * (HH * WW);

    // zero the a1 horizontal pads once (48 float4 writes)
    if (tid < 48) {
        int rr = tid / 6, g = tid % 6;
        a1_4[rr][g < 3 ? g : 64 + g] = make_float4(0.f, 0.f, 0.f, 0.f);
    }

    // stage x: 12*66 = 792 aligned float4 copies (zero halo)
    for (int i = tid; i < 12 * 66; i += 512) {
        int rr = i / 66, g = i - rr * 66;
        int gy = y0 - 2 + rr;
        float4 v = make_float4(0.f, 0.f, 0.f, 0.f);
        if (gy >= 0 && gy < HH && g >= 1 && g <= 64)
            v = *reinterpret_cast<const float4*>(xbase + (size_t)gy * WW + 4 * (g - 1));
        xs4[rr][g] = v;
    }
    __syncthreads();

    const int r = tid >> 6;
    const int l = tid & 63;
    const float* lwc = lw + c * 25;        // block-uniform -> s_load

    // 5x5: output col 4l+j taps gx = 4l+j+kx-2 -> local float idx j+kx+2 (2..9)
    float acc[4] = {0.f, 0.f, 0.f, 0.f};
    #pragma unroll
    for (int ky = 0; ky < 5; ++ky) {
        float4 g0 = xs4[r + ky][l];
        float4 g1 = xs4[r + ky][l + 1];
        float4 g2 = xs4[r + ky][l + 2];
        float rowv[12] = {g0.x, g0.y, g0.z, g0.w, g1.x, g1.y, g1.z, g1.w,
                          g2.x, g2.y, g2.z, g2.w};
        #pragma unroll
        for (int kx = 0; kx < 5; ++kx) {
            float wv = lwc[ky * 5 + kx];
            #pragma unroll
            for (int j = 0; j < 4; ++j)
                acc[j] = fmaf(wv, rowv[j + kx + 2], acc[j]);
        }
    }
    // write a1 cols 4l..4l+3 -> group l+3 (single aligned b128)
    a1_4[r][l + 3] = make_float4(acc[0], acc[1], acc[2], acc[3]);
    __syncthreads();

    // h-conv: window f = 4l..4l+27 from groups l..l+6 (7 x b128)
    float w28[28];
    #pragma unroll
    for (int t = 0; t < 7; ++t) {
        float4 g = a1_4[r][l + t];
        w28[4 * t + 0] = g.x; w28[4 * t + 1] = g.y;
        w28[4 * t + 2] = g.z; w28[4 * t + 3] = g.w;
    }
    float o[4] = {0.f, 0.f, 0.f, 0.f};
    const float* hwc = hw + c * 21;
    #pragma unroll
    for (int k = 0; k < 21; ++k) {
        float wv = hwc[k];
        #pragma unroll
        for (int j = 0; j < 4; ++j)
            o[j] = fmaf(wv, w28[j + k + 2], o[j]);   // tap xc=4l+j+k-10 -> idx j+k+2
    }

    unsigned short* dst = a2out + (size_t)(bc * HH + y0 + r) * WW + 4 * l;
    ushort4 pk;
    pk.x = f2bf(o[0]); pk.y = f2bf(o[1]); pk.z = f2bf(o[2]); pk.w = f2bf(o[3]);
    *reinterpret_cast<ushort4*>(dst) = pk;
}

// ---------------------------------------------------------------------------
// K2a: 21x1 vertical depthwise (pad 10), scatter-into-registers.
// block = (strip of 64 rows) x (b,c).  256 threads: half h = tid>>7 owns rows
// y0+32h..y0+32h+31, thread owns 2 adjacent columns (bf16x2 = uint loads/stores).
// Taps in SGPRs (block-uniform c).
// ---------------------------------------------------------------------------
__global__ __launch_bounds__(256) void k2a_v(
        const unsigned short* __restrict__ a2, const float* __restrict__ vw,
        unsigned short* __restrict__ a3) {
    const int strip = blockIdx.x;          // 0..3
    const int bc    = blockIdx.y;
    const int c     = bc & (CC - 1);
    const int y0    = strip * 64 + ((threadIdx.x >> 7) << 5);
    const int xc    = (threadIdx.x & 127) << 1;
    const float* vwc = vw + c * 21;        // s_load

    float acc0[32], acc1[32];
    #pragma unroll
    for (int i = 0; i < 32; ++i) { acc0[i] = 0.f; acc1[i] = 0.f; }

    const unsigned short* src = a2 + (size_t)bc * HH * WW + xc;
    #pragma unroll
    for (int rr = 0; rr < 52; ++rr) {
        int gy = y0 + rr - 10;
        float v0 = 0.f, v1 = 0.f;
        if (gy >= 0 && gy < HH) {
            unsigned int u = *reinterpret_cast<const unsigned int*>(src + (size_t)gy * WW);
            v0 = bflo(u); v1 = bfhi(u);
        }
        #pragma unroll
        for (int k = 0; k < 21; ++k) {
            int yl = rr - k;                       // compile-time prune
            if (yl >= 0 && yl < 32) {
                acc0[yl] = fmaf(vwc[k], v0, acc0[yl]);
                acc1[yl] = fmaf(vwc[k], v1, acc1[yl]);
            }
        }
    }
    unsigned short* dst = a3 + (size_t)bc * HH * WW + (size_t)y0 * WW + xc;
    #pragma unroll
    for (int y = 0; y < 32; ++y) {
        unsigned int pk = (unsigned int)f2bf(acc0[y]) |
                          ((unsigned int)f2bf(acc1[y]) << 16);
        *reinterpret_cast<unsigned int*>(dst + (size_t)y * WW) = pk;
    }
}

// ---------------------------------------------------------------------------
// K2b: 1x1 pointwise (64x64) + BN + sigmoid gate.  (unchanged this round)
// block = one (b, y) row.  256 threads: wave w -> co 16w..16w+15, lane l -> px 4l..4l+3.
// ---------------------------------------------------------------------------
__global__ __launch_bounds__(256) void k2b_pw(
        const unsigned short* __restrict__ a3, const float* __restrict__ x,
        const float* __restrict__ pw, const float* __restrict__ gamma,
        const float* __restrict__ beta, const float* __restrict__ mean,
        const float* __restrict__ var, float* __restrict__ out) {
    const int y   = blockIdx.x;
    const int b   = blockIdx.y;
    const int tid = threadIdx.x;

    __shared__ unsigned short a3s[64][256];   // 32 KB

    const unsigned short* abase = a3 + ((size_t)b * CC * HH + y) * WW;
    for (int i = tid; i < 64 * 64; i += 256) {
        int ci = i >> 6, q = (i & 63) << 2;
        ushort4 v = *reinterpret_cast<const ushort4*>(abase + (size_t)ci * HH * WW + q);
        *reinterpret_cast<ushort4*>(&a3s[ci][q]) = v;
    }
    __syncthreads();

    const int wu = __builtin_amdgcn_readfirstlane(tid >> 6);  // wave-uniform co group
    const int l  = tid & 63;

    float acc[64];
    #pragma unroll
    for (int i = 0; i < 64; ++i) acc[i] = 0.f;

    #pragma unroll 4
    for (int ci = 0; ci < 64; ++ci) {
        ushort4 raw = *reinterpret_cast<const ushort4*>(&a3s[ci][l << 2]);
        float p0 = bf2f(raw.x), p1 = bf2f(raw.y), p2 = bf2f(raw.z), p3 = bf2f(raw.w);
        #pragma unroll
        for (int j = 0; j < 16; ++j) {
            float wv = pw[(wu * 16 + j) * 64 + ci];   // scalar load
            acc[j * 4 + 0] = fmaf(wv, p0, acc[j * 4 + 0]);
            acc[j * 4 + 1] = fmaf(wv, p1, acc[j * 4 + 1]);
            acc[j * 4 + 2] = fmaf(wv, p2, acc[j * 4 + 2]);
            acc[j * 4 + 3] = fmaf(wv, p3, acc[j * 4 + 3]);
        }
    }

    #pragma unroll
    for (int j = 0; j < 16; ++j) {
        int co = wu * 16 + j;
        float inv = gamma[co] * rsqrtf(var[co] + 1e-5f);
        float sh  = beta[co] - mean[co] * inv;
        size_t off = (((size_t)b * CC + co) * HH + y) * WW + (l << 2);
        float4 xv = *reinterpret_cast<const float4*>(x + off);
        float4 r;
        float a;
        a = acc[j * 4 + 0] * inv + sh; r.x = xv.x / (1.f + __expf(-a));
        a = acc[j * 4 + 1] * inv + sh; r.y = xv.y / (1.f + __expf(-a));
        a = acc[j * 4 + 2] * inv + sh; r.z = xv.z / (1.f + __expf(-a));
        a = acc[j * 4 + 3] * inv + sh; r.w = xv.w / (1.f + __expf(-a));
        *reinterpret_cast<float4*>(out + off) = r;
    }
}

extern "C" void kernel_launch(void* const* d_in, const int* in_sizes, int n_in,
                              void* d_out, int out_size, void* d_ws, size_t ws_size,
                              hipStream_t stream) {
    const float* x     = (const float*)d_in[0];
    const float* lw    = (const float*)d_in[1];
    const float* hw    = (const float*)d_in[2];
    const float* vw    = (const float*)d_in[3];
    const float* pw    = (const float*)d_in[4];
    const float* gamma = (const float*)d_in[5];
    const float* beta  = (const float*)d_in[6];
    const float* mean  = (const float*)d_in[7];
    const float* var   = (const float*)d_in[8];
    float* out = (float*)d_out;

    // ws: attn2 (bf16) + attn3 (bf16) = 2 * 64 MiB = 128 MiB
    unsigned short* ws1 = (unsigned short*)d_ws;
    unsigned short* ws2 = ws1 + (size_t)BB * CC * HH * WW;

    k1_local_h<<<dim3(HH / 8, BB * CC), 512, 0, stream>>>(x, lw, hw, ws1);
    k2a_v<<<dim3(HH / 64, BB * CC), 256, 0, stream>>>(ws1, vw, ws2);
    k2b_pw<<<dim3(HH, BB), 256, 0, stream>>>(ws2, x, pw, gamma, beta, mean, var, out);
}

// Round 2
// 420.765 us; speedup vs baseline: 1.4113x; 1.4113x over previous
//
#include <hip/hip_runtime.h>
#include <hip/hip_bf16.h>

#define BB 8
#define CC 64
#define HH 256
#define WW 256

__device__ __forceinline__ unsigned short f2bf(float f) {
    __hip_bfloat16 h = __float2bfloat16(f);   // RNE
    return *reinterpret_cast<unsigned short*>(&h);
}
__device__ __forceinline__ float bf2f(unsigned short u) {
    unsigned int v = ((unsigned int)u) << 16;
    float r;
    __builtin_memcpy(&r, &v, 4);
    return r;
}
__device__ __forceinline__ float bflo(unsigned int u) {   // low ushort -> float
    unsigned int v = u << 16;
    float r; __builtin_memcpy(&r, &v, 4); return r;
}
__device__ __forceinline__ float bfhi(unsigned int u) {   // high ushort -> float
    unsigned int v = u & 0xffff0000u;
    float r; __builtin_memcpy(&r, &v, 4); return r;
}

// ---------------------------------------------------------------------------
// K1: fused 5x5 depthwise (pad 2) + 1x21 horizontal depthwise (pad 10)
// All LDS traffic as explicit float4 (ds_read_b128 / ds_write_b128, 16B lane
// stride -> conflict-free).  Strip of 8 rows x (b,c), 512 threads:
// wave w -> row w, lane l -> cols 4l..4l+3.  Writes attn2 as bf16.
// ---------------------------------------------------------------------------
__global__ __launch_bounds__(512) void k1_local_h(
        const float* __restrict__ x, const float* __restrict__ lw,
        const float* __restrict__ hw, unsigned short* __restrict__ a2out) {
    const int strip = blockIdx.x;          // 0..31
    const int bc    = blockIdx.y;          // 0..511
    const int c     = bc & (CC - 1);
    const int y0    = strip * 8;
    const int tid   = threadIdx.x;

    // xs4[rr][g]: x row (y0-2+rr), float4 group g covers gx = 4g-4 .. 4g-1 (g 0..65)
    __shared__ float4 xs4[12][66];
    // a1_4[r][g]: 5x5 output row (y0+r), group g covers xc = 4g-12 .. 4g-9 (g 0..69)
    // valid xc 0..255 -> groups 3..66; groups 0..2 / 67..69 are zero pad (h-conv pad 10)
    __shared__ float4 a1_4[8][70];

    const float* xbase = x + (size_t)bc * (HH * WW);

    // zero the a1 horizontal pads once (48 float4 writes)
    if (tid < 48) {
        int rr = tid / 6, g = tid % 6;
        a1_4[rr][g < 3 ? g : 64 + g] = make_float4(0.f, 0.f, 0.f, 0.f);
    }

    // stage x: 12*66 = 792 aligned float4 copies (zero halo)
    for (int i = tid; i < 12 * 66; i += 512) {
        int rr = i / 66, g = i - rr * 66;
        int gy = y0 - 2 + rr;
        float4 v = make_float4(0.f, 0.f, 0.f, 0.f);
        if (gy >= 0 && gy < HH && g >= 1 && g <= 64)
            v = *reinterpret_cast<const float4*>(xbase + (size_t)gy * WW + 4 * (g - 1));
        xs4[rr][g] = v;
    }
    __syncthreads();

    const int r = tid >> 6;
    const int l = tid & 63;
    const float* lwc = lw + c * 25;        // block-uniform -> s_load

    // 5x5: output col 4l+j taps gx = 4l+j+kx-2 -> local float idx j+kx+2 (2..9)
    float acc[4] = {0.f, 0.f, 0.f, 0.f};
    #pragma unroll
    for (int ky = 0; ky < 5; ++ky) {
        float4 g0 = xs4[r + ky][l];
        float4 g1 = xs4[r + ky][l + 1];
        float4 g2 = xs4[r + ky][l + 2];
        float rowv[12] = {g0.x, g0.y, g0.z, g0.w, g1.x, g1.y, g1.z, g1.w,
                          g2.x, g2.y, g2.z, g2.w};
        #pragma unroll
        for (int kx = 0; kx < 5; ++kx) {
            float wv = lwc[ky * 5 + kx];
            #pragma unroll
            for (int j = 0; j < 4; ++j)
                acc[j] = fmaf(wv, rowv[j + kx + 2], acc[j]);
        }
    }
    // write a1 cols 4l..4l+3 -> group l+3 (single aligned b128)
    a1_4[r][l + 3] = make_float4(acc[0], acc[1], acc[2], acc[3]);
    __syncthreads();

    // h-conv: window f = 4l..4l+27 from groups l..l+6 (7 x b128)
    float w28[28];
    #pragma unroll
    for (int t = 0; t < 7; ++t) {
        float4 g = a1_4[r][l + t];
        w28[4 * t + 0] = g.x; w28[4 * t + 1] = g.y;
        w28[4 * t + 2] = g.z; w28[4 * t + 3] = g.w;
    }
    float o[4] = {0.f, 0.f, 0.f, 0.f};
    const float* hwc = hw + c * 21;
    #pragma unroll
    for (int k = 0; k < 21; ++k) {
        float wv = hwc[k];
        #pragma unroll
        for (int j = 0; j < 4; ++j)
            o[j] = fmaf(wv, w28[j + k + 2], o[j]);   // tap xc=4l+j+k-10 -> idx j+k+2
    }

    unsigned short* dst = a2out + (size_t)(bc * HH + y0 + r) * WW + 4 * l;
    ushort4 pk;
    pk.x = f2bf(o[0]); pk.y = f2bf(o[1]); pk.z = f2bf(o[2]); pk.w = f2bf(o[3]);
    *reinterpret_cast<ushort4*>(dst) = pk;
}

// ---------------------------------------------------------------------------
// K2a: 21x1 vertical depthwise (pad 10), gather form through LDS.
// block = (strip of 64 rows) x (b,c).  256 threads.
// Stage 84x256 bf16 tile (43 KB) with uint4 loads; thread owns 8 cols x 8 rows.
// Per output row: 21 ds_read_b128 + 8 named scalar accumulators (no arrays ->
// no runtime indexing -> no scratch).  #pragma unroll 1 on the row loop blocks
// cross-row CSE so registers stay ~35.
// ---------------------------------------------------------------------------
__global__ __launch_bounds__(256) void k2a_v(
        const unsigned short* __restrict__ a2, const float* __restrict__ vw,
        unsigned short* __restrict__ a3) {
    const int strip = blockIdx.x;          // 0..3
    const int bc    = blockIdx.y;
    const int c     = bc & (CC - 1);
    const int y0    = strip * 64;
    const int tid   = threadIdx.x;

    __shared__ unsigned short lds[84][256];   // 43 KB, row stride 512 B

    const unsigned short* sbase = a2 + (size_t)bc * (HH * WW);
    // stage rows y0-10 .. y0+73 (zero halo); 84*32 = 2688 uint4 chunks
    for (int i = tid; i < 84 * 32; i += 256) {
        int row = i >> 5, g = i & 31;
        int gy = y0 - 10 + row;
        uint4 v = make_uint4(0u, 0u, 0u, 0u);
        if (gy >= 0 && gy < HH)
            v = *reinterpret_cast<const uint4*>(sbase + (size_t)gy * WW + g * 8);
        *reinterpret_cast<uint4*>(&lds[row][g * 8]) = v;
    }
    __syncthreads();

    const float* vwc = vw + c * 21;        // block-uniform -> s_load
    float w[21];
    #pragma unroll
    for (int k = 0; k < 21; ++k) w[k] = vwc[k];

    const int cg = tid & 31;               // 8-col group: cols 8cg..8cg+7
    const int rg = tid >> 5;               // 8-row group: rows y0+8rg..y0+8rg+7
    unsigned short* dst = a3 + (size_t)bc * (HH * WW)
                        + (size_t)(y0 + rg * 8) * WW + cg * 8;

    #pragma unroll 1
    for (int i = 0; i < 8; ++i) {
        float s0 = 0.f, s1 = 0.f, s2 = 0.f, s3 = 0.f;
        float s4 = 0.f, s5 = 0.f, s6 = 0.f, s7 = 0.f;
        #pragma unroll
        for (int k = 0; k < 21; ++k) {
            // out[y0+8rg+i] += w[k] * in[y0+8rg+i+k-10]; staged index = 8rg+i+k
            uint4 u = *reinterpret_cast<const uint4*>(&lds[rg * 8 + i + k][cg * 8]);
            float wk = w[k];
            s0 = fmaf(wk, bflo(u.x), s0); s1 = fmaf(wk, bfhi(u.x), s1);
            s2 = fmaf(wk, bflo(u.y), s2); s3 = fmaf(wk, bfhi(u.y), s3);
            s4 = fmaf(wk, bflo(u.z), s4); s5 = fmaf(wk, bfhi(u.z), s5);
            s6 = fmaf(wk, bflo(u.w), s6); s7 = fmaf(wk, bfhi(u.w), s7);
        }
        uint4 o;
        o.x = (unsigned int)f2bf(s0) | ((unsigned int)f2bf(s1) << 16);
        o.y = (unsigned int)f2bf(s2) | ((unsigned int)f2bf(s3) << 16);
        o.z = (unsigned int)f2bf(s4) | ((unsigned int)f2bf(s5) << 16);
        o.w = (unsigned int)f2bf(s6) | ((unsigned int)f2bf(s7) << 16);
        *reinterpret_cast<uint4*>(dst + (size_t)i * WW) = o;
    }
}

// ---------------------------------------------------------------------------
// K2b: 1x1 pointwise (64x64) + BN + sigmoid gate.  (unchanged this round)
// block = one (b, y) row.  256 threads: wave w -> co 16w..16w+15, lane l -> px 4l..4l+3.
// ---------------------------------------------------------------------------
__global__ __launch_bounds__(256) void k2b_pw(
        const unsigned short* __restrict__ a3, const float* __restrict__ x,
        const float* __restrict__ pw, const float* __restrict__ gamma,
        const float* __restrict__ beta, const float* __restrict__ mean,
        const float* __restrict__ var, float* __restrict__ out) {
    const int y   = blockIdx.x;
    const int b   = blockIdx.y;
    const int tid = threadIdx.x;

    __shared__ unsigned short a3s[64][256];   // 32 KB

    const unsigned short* abase = a3 + ((size_t)b * CC * HH + y) * WW;
    for (int i = tid; i < 64 * 64; i += 256) {
        int ci = i >> 6, q = (i & 63) << 2;
        ushort4 v = *reinterpret_cast<const ushort4*>(abase + (size_t)ci * HH * WW + q);
        *reinterpret_cast<ushort4*>(&a3s[ci][q]) = v;
    }
    __syncthreads();

    const int wu = __builtin_amdgcn_readfirstlane(tid >> 6);  // wave-uniform co group
    const int l  = tid & 63;

    float acc[64];
    #pragma unroll
    for (int i = 0; i < 64; ++i) acc[i] = 0.f;

    #pragma unroll 4
    for (int ci = 0; ci < 64; ++ci) {
        ushort4 raw = *reinterpret_cast<const ushort4*>(&a3s[ci][l << 2]);
        float p0 = bf2f(raw.x), p1 = bf2f(raw.y), p2 = bf2f(raw.z), p3 = bf2f(raw.w);
        #pragma unroll
        for (int j = 0; j < 16; ++j) {
            float wv = pw[(wu * 16 + j) * 64 + ci];   // scalar load
            acc[j * 4 + 0] = fmaf(wv, p0, acc[j * 4 + 0]);
            acc[j * 4 + 1] = fmaf(wv, p1, acc[j * 4 + 1]);
            acc[j * 4 + 2] = fmaf(wv, p2, acc[j * 4 + 2]);
            acc[j * 4 + 3] = fmaf(wv, p3, acc[j * 4 + 3]);
        }
    }

    #pragma unroll
    for (int j = 0; j < 16; ++j) {
        int co = wu * 16 + j;
        float inv = gamma[co] * rsqrtf(var[co] + 1e-5f);
        float sh  = beta[co] - mean[co] * inv;
        size_t off = (((size_t)b * CC + co) * HH + y) * WW + (l << 2);
        float4 xv = *reinterpret_cast<const float4*>(x + off);
        float4 r;
        float a;
        a = acc[j * 4 + 0] * inv + sh; r.x = xv.x / (1.f + __expf(-a));
        a = acc[j * 4 + 1] * inv + sh; r.y = xv.y / (1.f + __expf(-a));
        a = acc[j * 4 + 2] * inv + sh; r.z = xv.z / (1.f + __expf(-a));
        a = acc[j * 4 + 3] * inv + sh; r.w = xv.w / (1.f + __expf(-a));
        *reinterpret_cast<float4*>(out + off) = r;
    }
}

extern "C" void kernel_launch(void* const* d_in, const int* in_sizes, int n_in,
                              void* d_out, int out_size, void* d_ws, size_t ws_size,
                              hipStream_t stream) {
    const float* x     = (const float*)d_in[0];
    const float* lw    = (const float*)d_in[1];
    const float* hw    = (const float*)d_in[2];
    const float* vw    = (const float*)d_in[3];
    const float* pw    = (const float*)d_in[4];
    const float* gamma = (const float*)d_in[5];
    const float* beta  = (const float*)d_in[6];
    const float* mean  = (const float*)d_in[7];
    const float* var   = (const float*)d_in[8];
    float* out = (float*)d_out;

    // ws: attn2 (bf16) + attn3 (bf16) = 2 * 64 MiB = 128 MiB
    unsigned short* ws1 = (unsigned short*)d_ws;
    unsigned short* ws2 = ws1 + (size_t)BB * CC * HH * WW;

    k1_local_h<<<dim3(HH / 8, BB * CC), 512, 0, stream>>>(x, lw, hw, ws1);
    k2a_v<<<dim3(HH / 64, BB * CC), 256, 0, stream>>>(ws1, vw, ws2);
    k2b_pw<<<dim3(HH, BB), 256, 0, stream>>>(ws2, x, pw, gamma, beta, mean, var, out);
}